// Round 9
// baseline (4359.576 us; speedup 1.0000x reference)
//
#include <hip/hip_runtime.h>
#include <stdint.h>

#define V_ 16000
#define E_ 512
#define H_ 1024
#define B_ 32
#define T_ 64
#define NG_ 3072        // 3*H rows per weight matrix
#define NR_ 6144        // virtual rows in gru gemm (ih + hh)
#define IHB_ 96         // ih blocks (3072/32)
#define TPAD_ 8         // u64 stride per batch slot: 1 slot per 64B cache line

typedef float f32x4 __attribute__((ext_vector_type(4)));
typedef unsigned long long u64;

__device__ __forceinline__ unsigned int fkey(float f) {
    unsigned int u = __float_as_uint(f);
    return (u & 0x80000000u) ? ~u : (u | 0x80000000u);
}

__global__ void init_kernel(const float* __restrict__ hidden,
                            float* __restrict__ h0, float* __restrict__ h1,
                            u64* __restrict__ tokpk) {
    int idx = blockIdx.x * blockDim.x + threadIdx.x;
    if (idx < B_ * H_) {
        h0[idx] = hidden[idx];
        h1[idx] = hidden[B_ * H_ + idx];
    }
    if (idx < T_ * B_ * TPAD_) tokpk[idx] = 0ull;
}

// ---------------------------------------------------------------------------
// Champion gemm_core (r5/r8 = 4334us), 512 threads, verbatim.
// 32 rows x 32 batch x K tile. Each thread stages 1 W row-chunk + 1 A
// row-chunk; 1-chunk-ahead register prefetch; XOR-swizzled f32x4 LDS slots.
// Compute: ks = tid>>6 (8-way K-split), 2 kk per chunk, acc[4][4].
// ---------------------------------------------------------------------------
__device__ __forceinline__ void gemm_core(
    const float* wp, const float* ap,
    int nch, float* lds, int tid, float acc[4][4])
{
    const int k4s = tid & 15;
    const int r   = tid >> 4;                       // 0..31
    const int dW  = (r << 6) + ((k4s ^ (r & 7)) << 2);
    const int ks   = tid >> 6;                      // 0..7
    const int lane = tid & 63;
    const int vg = lane >> 3, bg = lane & 7;

    f32x4 tW = *(const f32x4*)(wp + (k4s << 2));
    f32x4 tA = *(const f32x4*)(ap + (k4s << 2));
    *(f32x4*)&lds[dW] = tW;
    *(f32x4*)&lds[2048 + dW] = tA;
    __syncthreads();

    int cur = 0;
    for (int c = 0; c < nch; c++) {
        if (c + 1 < nch) {
            const int nko = (c + 1) << 6;
            tW = *(const f32x4*)(wp + nko + (k4s << 2));
            tA = *(const f32x4*)(ap + nko + (k4s << 2));
        }
        const float* Wb = &lds[cur * 4096];
        const float* Ab = &lds[cur * 4096 + 2048];
        #pragma unroll
        for (int kk = 0; kk < 2; kk++) {
            const int k4 = ks * 2 + kk;
            f32x4 ww[4], ha[4];
            #pragma unroll
            for (int vi = 0; vi < 4; vi++)
                ww[vi] = *(const f32x4*)&Wb[((vg + 8*vi) << 6) + ((k4 ^ vg) << 2)];
            #pragma unroll
            for (int j = 0; j < 4; j++)
                ha[j] = *(const f32x4*)&Ab[((bg + 8*j) << 6) + ((k4 ^ bg) << 2)];
            #pragma unroll
            for (int vi = 0; vi < 4; vi++)
                #pragma unroll
                for (int j = 0; j < 4; j++)
                    acc[vi][j] += ww[vi].x*ha[j].x + ww[vi].y*ha[j].y
                                + ww[vi].z*ha[j].z + ww[vi].w*ha[j].w;
        }
        if (c + 1 < nch) {
            float* Wo = &lds[(cur ^ 1) * 4096];
            *(f32x4*)&Wo[dW] = tW;
            *(f32x4*)&Wo[2048 + dW] = tA;
        }
        __syncthreads();
        cur ^= 1;
    }
}

__device__ __forceinline__ void ks_reduce(float* lds, int tid,
                                          float acc[4][4], float tv[16])
{
    const int ks = tid >> 6, lane = tid & 63;
    float* dst = &lds[(ks * 64 + lane) * 17];       // [8][64][17]
    #pragma unroll
    for (int vi = 0; vi < 4; vi++)
        #pragma unroll
        for (int j = 0; j < 4; j++) dst[vi*4 + j] = acc[vi][j];
    __syncthreads();
    if (tid < 64) {
        #pragma unroll
        for (int c = 0; c < 16; c++) {
            float s = 0.f;
            #pragma unroll
            for (int k = 0; k < 8; k++) s += lds[(k*64 + tid)*17 + c];
            tv[c] = s;
        }
    }
}

__global__ __launch_bounds__(512) void gemm_gru(
    const float* __restrict__ Wih, const float* __restrict__ Whh, int Kih,
    const float* __restrict__ xbase, int xld,
    const float* __restrict__ embed, const u64* __restrict__ tokprev,
    int t, int tmode,
    const float* __restrict__ hprev,
    float* __restrict__ gbuf)
{
    __shared__ float lds[8704];
    const int tid = threadIdx.x;
    const int blk = blockIdx.x;
    const int r = tid >> 4;                         // 0..31

    const float *wp, *ap;
    int nch;
    if (blk < IHB_) {
        const int n0 = blk * 32;
        wp = Wih + (size_t)(n0 + r) * Kih;
        if (tmode) {
            int tok = 0;
            if (t > 0)
                tok = (int)(0xFFFFFFFFu -
                            (unsigned)(tokprev[(size_t)r * TPAD_] & 0xFFFFFFFFull));
            ap = embed + (size_t)tok * Kih;
        } else {
            ap = xbase + (size_t)r * xld;
        }
        nch = Kih >> 6;
    } else {
        const int n0 = (blk - IHB_) * 32;
        wp = Whh + (size_t)(n0 + r) * H_;
        ap = hprev + (size_t)r * H_;
        nch = H_ >> 6;
    }

    float acc[4][4] = {};
    gemm_core(wp, ap, nch, lds, tid, acc);
    float tv[16];
    ks_reduce(lds, tid, acc, tv);
    if (tid < 64) {
        const int vgr = tid >> 3, bgr = tid & 7;
        const int nout0 = blk * 32;
        #pragma unroll
        for (int vi = 0; vi < 4; vi++)
            #pragma unroll
            for (int j = 0; j < 4; j++)
                gbuf[(size_t)(bgr + 8*j) * NR_ + nout0 + vgr + 8*vi] = tv[vi*4+j];
    }
}

__global__ __launch_bounds__(256) void combine_kernel(
    const float* __restrict__ gbuf,
    const float* __restrict__ bih, const float* __restrict__ bhh,
    const float* __restrict__ hprev, float* __restrict__ hnew)
{
    const int idx = blockIdx.x * 256 + threadIdx.x;   // 0..32767
    const int b = idx >> 10, i = idx & 1023;
    const float* gb = gbuf + (size_t)b * NR_;
    const float gir = gb[i],        giz = gb[H_ + i],        gin = gb[2*H_ + i];
    const float ghr = gb[NG_ + i],  ghz = gb[NG_ + H_ + i],  ghn = gb[NG_ + 2*H_ + i];
    const float Sr = gir + ghr + bih[i] + bhh[i];
    const float Sz = giz + ghz + bih[H_ + i] + bhh[H_ + i];
    const float rr = 1.f / (1.f + expf(-Sr));
    const float zz = 1.f / (1.f + expf(-Sz));
    const float nn = tanhf(gin + bih[2*H_ + i] + rr * (ghn + bhh[2*H_ + i]));
    const float hp = hprev[(size_t)b * H_ + i];
    hnew[(size_t)b * H_ + i] = (1.f - zz) * nn + zz * hp;
}

// Logits (32 vocab rows/block, grid 500, 512 thr) + bias + nt-store + argmax.
// Argmax fan-in: one atomicMax per (block,batch) to a PADDED slot (1 batch
// per 64B cache line) -- line-level RMW serialization 4000 -> 500 per line.
__global__ __launch_bounds__(512) void logits_kernel(
    const float* __restrict__ h1, const float* __restrict__ Wout,
    const float* __restrict__ bout, float* __restrict__ out_t,
    u64* __restrict__ tokpk_t)
{
    __shared__ float lds[10272];   // stream 8192 | red 8704, totl 1056, am 512
    const int tid = threadIdx.x;
    const int r = tid >> 4;                          // 0..31
    const int v0 = blockIdx.x * 32;
    const float* wp = Wout + (size_t)(v0 + r) * H_;
    const float* ap = h1 + (size_t)r * H_;

    float acc[4][4] = {};
    gemm_core(wp, ap, H_ >> 6, lds, tid, acc);
    float tv[16];
    ks_reduce(lds, tid, acc, tv);

    float* totl = lds + 8704;                        // [32][33]
    u64*   am   = (u64*)(lds + 8704 + 1056);         // [32][8]
    if (tid < 64) {
        const int vgr = tid >> 3, bgr = tid & 7;
        #pragma unroll
        for (int vi = 0; vi < 4; vi++) {
            const float bo = bout[v0 + vgr + 8*vi];
            #pragma unroll
            for (int j = 0; j < 4; j++) tv[vi*4+j] += bo;
        }
        #pragma unroll
        for (int vi = 0; vi < 4; vi++)
            #pragma unroll
            for (int j = 0; j < 4; j++)
                totl[(bgr + 8*j) * 33 + vgr + 8*vi] = tv[vi*4+j];
        #pragma unroll
        for (int j = 0; j < 4; j++) {
            u64 best = 0ull;
            #pragma unroll
            for (int vi = 0; vi < 4; vi++) {
                const int v = v0 + vgr + 8*vi;
                u64 p = ((u64)fkey(tv[vi*4+j]) << 32)
                      | (u64)(0xFFFFFFFFu - (unsigned)v);
                best = p > best ? p : best;
            }
            am[(bgr + 8*j) * 8 + vgr] = best;
        }
    }
    __syncthreads();
    if (tid < 64) {
        const int b = tid >> 1, half = tid & 1;
        #pragma unroll
        for (int q = 0; q < 4; q++) {
            f32x4 o;
            o.x = totl[b*33 + half*16 + q*4 + 0];
            o.y = totl[b*33 + half*16 + q*4 + 1];
            o.z = totl[b*33 + half*16 + q*4 + 2];
            o.w = totl[b*33 + half*16 + q*4 + 3];
            __builtin_nontemporal_store(
                o, (f32x4*)(out_t + (size_t)b * V_ + v0 + half*16 + q*4));
        }
    }
    if (tid < 32) {
        u64 best = 0ull;
        #pragma unroll
        for (int q = 0; q < 8; q++) {
            u64 p = am[tid*8 + q];
            best = p > best ? p : best;
        }
        atomicMax(&tokpk_t[(size_t)tid * TPAD_], best);
    }
}

extern "C" void kernel_launch(void* const* d_in, const int* in_sizes, int n_in,
                              void* d_out, int out_size, void* d_ws, size_t ws_size,
                              hipStream_t stream) {
    const float* hidden = (const float*)d_in[0];
    const float* embed  = (const float*)d_in[1];
    const float* Wih0   = (const float*)d_in[2];
    const float* Whh0   = (const float*)d_in[3];
    const float* bih0   = (const float*)d_in[4];
    const float* bhh0   = (const float*)d_in[5];
    const float* Wih1   = (const float*)d_in[6];
    const float* Whh1   = (const float*)d_in[7];
    const float* bih1   = (const float*)d_in[8];
    const float* bhh1   = (const float*)d_in[9];
    const float* Wout   = (const float*)d_in[10];
    const float* bout   = (const float*)d_in[11];
    float* out = (float*)d_out;

    const int BH = B_ * H_;
    float* ws = (float*)d_ws;
    float* h0buf = ws;                        // [2][B][H]
    float* h1buf = ws + 2 * BH;               // [2][B][H]
    float* gbuf  = ws + 4 * BH;               // [B][NR_]
    u64* tokpk = (u64*)(ws + 4 * BH + B_ * NR_);  // [T][B*TPAD_]

    init_kernel<<<128, 256, 0, stream>>>(hidden, h0buf, h1buf, tokpk);

    for (int t = 0; t < T_; t++) {
        const int rp = t & 1, wp = (t + 1) & 1;
        const u64* tokprev = tokpk + (size_t)(t > 0 ? t - 1 : 0) * B_ * TPAD_;

        gemm_gru<<<NR_ / 32, 512, 0, stream>>>(
            Wih0, Whh0, E_, nullptr, 0, embed, tokprev, t, /*tmode=*/1,
            h0buf + (size_t)rp * BH, gbuf);
        combine_kernel<<<128, 256, 0, stream>>>(
            gbuf, bih0, bhh0, h0buf + (size_t)rp * BH, h0buf + (size_t)wp * BH);

        gemm_gru<<<NR_ / 32, 512, 0, stream>>>(
            Wih1, Whh1, H_, h0buf + (size_t)wp * BH, H_, embed, tokprev, 0,
            /*tmode=*/0, h1buf + (size_t)rp * BH, gbuf);
        combine_kernel<<<128, 256, 0, stream>>>(
            gbuf, bih1, bhh1, h1buf + (size_t)rp * BH, h1buf + (size_t)wp * BH);

        logits_kernel<<<V_ / 32, 512, 0, stream>>>(
            h1buf + (size_t)wp * BH, Wout, bout,
            out + (size_t)t * B_ * V_, tokpk + (size_t)t * B_ * TPAD_);
    }
}